// Round 3
// baseline (64.792 us; speedup 1.0000x reference)
//
#include <hip/hip_runtime.h>

#define M_AG   4608
#define NPO    1536
#define D_DIM  256
#define H_DIM  512
#define NBIG   1536
#define GRID_SZ 256
#define NB_CAP 48

typedef __attribute__((ext_vector_type(8))) short short8;
typedef __attribute__((ext_vector_type(4))) float f32x4;
typedef unsigned short ushort_t;

__device__ __forceinline__ ushort_t f2bf(float f) {
  unsigned int u = __builtin_bit_cast(unsigned int, f);
  unsigned int r = (u + 0x7FFFu + ((u >> 16) & 1u)) >> 16;   // RNE, finite inputs
  return (ushort_t)r;
}
__device__ __forceinline__ float bf2f(ushort_t u) {
  return __builtin_bit_cast(float, (unsigned int)u << 16);
}
__device__ __forceinline__ float tanh_fast(float x) {
  // tanh(x) = 1 - 2/(exp(2x)+1); v_exp_f32 is 2^x so scale by 2*log2(e)
  float e = __builtin_amdgcn_exp2f(x * 2.8853900817779268f);
  return 1.f - 2.f * __builtin_amdgcn_rcpf(e + 1.f);
}
// async global->LDS, 16B per lane. LDS dest must be wave-uniform base + lane*16.
__device__ __forceinline__ void gl_lds16(const ushort_t* g, ushort_t* l) {
  __builtin_amdgcn_global_load_lds(
      (const __attribute__((address_space(1))) unsigned int*)g,
      (__attribute__((address_space(3))) unsigned int*)l, 16, 0, 0);
}

#define PS_BLK  576
#define PW_BLK  576
#define PW2_BLK 192
#define SCAN_BLK 1152

// ---------------------------------------------------------------------------
// prep: block-role dispatch.
//  [0,576)          pack S    -> Sc  [32][4608][8] bf16 chunked
//  [576,1152)       pack W    -> Wc  [3][32][1536][8]  (n-concat W_out|W_in|W1)
//  [1152,1344)      pack W2   -> W2c [3][64][256][8]
//  [1344,2496)      neighbor scan, 4 agents/block (one wave each), ballot-ordered
// ---------------------------------------------------------------------------
__global__ __launch_bounds__(256) void prep(
    const float* __restrict__ S, const float* __restrict__ W_out,
    const float* __restrict__ W_in, const float* __restrict__ W1,
    const float* __restrict__ W2,
    const int* __restrict__ roles, const int* __restrict__ positions,
    ushort_t* __restrict__ Sc, ushort_t* __restrict__ Wc,
    ushort_t* __restrict__ W2c, int4* __restrict__ stats, int* __restrict__ nb)
{
  __shared__ int pk[M_AG];   // x | y<<8 | role<<16
  const int b = blockIdx.x, t = threadIdx.x;

  if (b < PS_BLK) {
    int idx = b * 256 + t;                      // < 32*4608
    int kc = idx / M_AG, m = idx - kc * M_AG;
    const float* p = S + (size_t)m * D_DIM + kc * 8;
    ushort_t* d = Sc + (size_t)idx * 8;
#pragma unroll
    for (int j = 0; j < 8; ++j) d[j] = f2bf(p[j]);
  } else if (b < PS_BLK + PW_BLK) {
    int idx = (b - PS_BLK) * 256 + t;           // < 3*32*1536
    int org = idx / (32 * NBIG);
    int rem = idx - org * (32 * NBIG);
    int kc = rem / NBIG, n = rem - kc * NBIG;
    int which = n >> 9, nl = n & 511;
    const float* Wsel = (which == 0 ? W_out : which == 1 ? W_in : W1);
    const float* p = Wsel + (size_t)org * (D_DIM * H_DIM) + (size_t)kc * 8 * H_DIM + nl;
    ushort_t* d = Wc + (size_t)idx * 8;
#pragma unroll
    for (int j = 0; j < 8; ++j) d[j] = f2bf(p[(size_t)j * H_DIM]);
  } else if (b < PS_BLK + PW_BLK + PW2_BLK) {
    int idx = (b - PS_BLK - PW_BLK) * 256 + t;  // < 3*64*256
    int org = idx / (64 * D_DIM);
    int rem = idx - org * (64 * D_DIM);
    int kc = rem >> 8, n = rem & 255;
    const float* p = W2 + (size_t)org * (H_DIM * D_DIM) + (size_t)kc * 8 * D_DIM + n;
    ushort_t* d = W2c + (size_t)idx * 8;
#pragma unroll
    for (int j = 0; j < 8; ++j) d[j] = f2bf(p[(size_t)j * D_DIM]);
  } else {
    // neighbor scan
    for (int j = t; j < M_AG; j += 256) {
      int2 p = ((const int2*)positions)[j];
      pk[j] = p.x | (p.y << 8) | (roles[j] << 16);
    }
    __syncthreads();
    const int w = t >> 6, l = t & 63;
    const int i = (b - (PS_BLK + PW_BLK + PW2_BLK)) * 4 + w;   // agent
    const int pi = pk[i];
    const int xi = pi & 255, yi = (pi >> 8) & 255;
    const int my_org = (i >= NPO) + (i >= 2 * NPO);   // org_ids = repeat(arange(3),1536)
    int nbn = 0, c_mass = 0, c_fi = 0, c_enemy = 0;
    for (int base = 0; base < M_AG; base += 64) {
      int j = base + l;
      int pj = pk[j];
      int dx = (pj & 255) - xi, dy = ((pj >> 8) & 255) - yi;
      int rj = pj >> 16;
      bool in_r = (dx * dx + dy * dy <= 25) && (j != i);
      int oj = (j >= NPO) + (j >= 2 * NPO);
      bool same = in_r && (oj == my_org);
      unsigned long long ms = __ballot(same);
      if (same) {
        int slot = nbn + __popcll(ms & ((1ull << l) - 1ull));
        if (slot < NB_CAP) nb[i * NB_CAP + slot] = j;   // ascending j: canonical order
      }
      nbn    += __popcll(ms);
      c_mass += __popcll(__ballot(same && rj == 0));
      c_fi   += __popcll(__ballot(same && rj == 1));
      c_enemy+= __popcll(__ballot(in_r && (oj != my_org) && rj == 1));
    }
    if (l == 0) stats[i] = make_int4(nbn, c_mass, c_fi, c_enemy);
  }
}

// ---------------------------------------------------------------------------
// gemm_fused: [A|B|H1] = tanh(S*[W_out|W_in|W1] + bias). m97 structure:
// 128x128 tile, BK=32, global_load_lds width-16, 4 waves (2x2), 4x4 frags.
// ---------------------------------------------------------------------------
__global__ __launch_bounds__(256) void gemm_fused(
    const ushort_t* __restrict__ Sc, const ushort_t* __restrict__ Wc,
    const float* __restrict__ b_out, const float* __restrict__ b_in,
    const float* __restrict__ b1,
    ushort_t* __restrict__ Abf, ushort_t* __restrict__ Bbf,
    ushort_t* __restrict__ Hc)
{
  __shared__ ushort_t As[4096], Bs[4096];   // [4 kgroup][128 row][8], 8 KB each
  const int t = threadIdx.x;
  const int w = t >> 6, l = t & 63;
  const int wm = w >> 1, wn = w & 1;
  const int lr = l & 15, lg = l >> 4;
  const int n0 = blockIdx.x * 128, m0 = blockIdx.y * 128;
  const int org = m0 / NPO;
  const int c0 = t, c1 = t + 256;               // staged 16B chunks
  const int g0 = c0 >> 7, r0 = c0 & 127;
  const int g1 = c1 >> 7, r1 = c1 & 127;

  f32x4 acc[4][4] = {};
  const short8* Ap = (const short8*)As;
  const short8* Bp = (const short8*)Bs;

  for (int ks = 0; ks < 8; ++ks) {
    const int kc8 = ks * 4;
    __syncthreads();
    gl_lds16(Sc + ((size_t)(kc8 + g0) * M_AG + m0 + r0) * 8, As + c0 * 8);
    gl_lds16(Sc + ((size_t)(kc8 + g1) * M_AG + m0 + r1) * 8, As + c1 * 8);
    gl_lds16(Wc + ((size_t)(org * 32 + kc8 + g0) * NBIG + n0 + r0) * 8, Bs + c0 * 8);
    gl_lds16(Wc + ((size_t)(org * 32 + kc8 + g1) * NBIG + n0 + r1) * 8, Bs + c1 * 8);
    __syncthreads();   // compiler drains vmcnt(0) before s_barrier
    short8 af[4], bfr[4];
#pragma unroll
    for (int mi = 0; mi < 4; ++mi) af[mi]  = Ap[lg * 128 + wm * 64 + mi * 16 + lr];
#pragma unroll
    for (int ni = 0; ni < 4; ++ni) bfr[ni] = Bp[lg * 128 + wn * 64 + ni * 16 + lr];
#pragma unroll
    for (int mi = 0; mi < 4; ++mi)
#pragma unroll
      for (int ni = 0; ni < 4; ++ni)
        acc[mi][ni] = __builtin_amdgcn_mfma_f32_16x16x32_bf16(af[mi], bfr[ni], acc[mi][ni], 0, 0, 0);
  }

  const int which = n0 >> 9;
  const int nlb = n0 & 511;
  const float* bias = (which == 0 ? b_out : which == 1 ? b_in : b1) + org * H_DIM;
  ushort_t* dst = (which == 0) ? Abf : Bbf;
#pragma unroll
  for (int ni = 0; ni < 4; ++ni) {
    const int nl = nlb + wn * 64 + ni * 16 + lr;
    const float bb = bias[nl];
#pragma unroll
    for (int mi = 0; mi < 4; ++mi)
#pragma unroll
      for (int r = 0; r < 4; ++r) {
        const int row = m0 + wm * 64 + mi * 16 + lg * 4 + r;
        ushort_t hv = f2bf(tanh_fast(acc[mi][ni][r] + bb));
        if (which < 2) dst[(size_t)row * H_DIM + nl] = hv;
        else           Hc[((size_t)(nl >> 3) * M_AG + row) * 8 + (nl & 7)] = hv;
      }
  }
}

// ---------------------------------------------------------------------------
// sp_final: blocks [0,288) compute SP=H1*W2+b2 (64x64 tile, K=512) and write
// out[row][0:256] = has_nb ? states+0.1*SP : states.  Blocks [288,1440):
// per-agent finish (wave per agent): score dots + energy/role epilogue.
// ---------------------------------------------------------------------------
__global__ __launch_bounds__(256) void sp_final(
    const ushort_t* __restrict__ Hc, const ushort_t* __restrict__ W2c,
    const float* __restrict__ b2, const float* __restrict__ states,
    const ushort_t* __restrict__ Abf, const ushort_t* __restrict__ Bbf,
    const float* __restrict__ energies, const float* __restrict__ resource_grid,
    const int* __restrict__ roles, const int* __restrict__ positions,
    const int4* __restrict__ stats, const int* __restrict__ nb,
    float* __restrict__ out)
{
  __shared__ ushort_t As[2048], Bs[2048];   // [4][64][8]
  const int b = blockIdx.x, t = threadIdx.x;
  const int w = t >> 6, l = t & 63;

  if (b < 288) {
    const int wm = w >> 1, wn = w & 1;
    const int lr = l & 15, lg = l >> 4;
    const int n0 = (b & 3) * 64, m0 = (b >> 2) * 64;
    const int org = m0 / NPO;
    const int g0 = t >> 6, r0 = t & 63;
    f32x4 acc[2][2] = {};
    const short8* Ap = (const short8*)As;
    const short8* Bp = (const short8*)Bs;
    for (int ks = 0; ks < 16; ++ks) {
      const int kc8 = ks * 4;
      __syncthreads();
      gl_lds16(Hc  + ((size_t)(kc8 + g0) * M_AG + m0 + r0) * 8, As + t * 8);
      gl_lds16(W2c + ((size_t)(org * 64 + kc8 + g0) * D_DIM + n0 + r0) * 8, Bs + t * 8);
      __syncthreads();
      short8 a0 = Ap[lg * 64 + wm * 32 + lr],      a1 = Ap[lg * 64 + wm * 32 + 16 + lr];
      short8 q0 = Bp[lg * 64 + wn * 32 + lr],      q1 = Bp[lg * 64 + wn * 32 + 16 + lr];
      acc[0][0] = __builtin_amdgcn_mfma_f32_16x16x32_bf16(a0, q0, acc[0][0], 0, 0, 0);
      acc[0][1] = __builtin_amdgcn_mfma_f32_16x16x32_bf16(a0, q1, acc[0][1], 0, 0, 0);
      acc[1][0] = __builtin_amdgcn_mfma_f32_16x16x32_bf16(a1, q0, acc[1][0], 0, 0, 0);
      acc[1][1] = __builtin_amdgcn_mfma_f32_16x16x32_bf16(a1, q1, acc[1][1], 0, 0, 0);
    }
#pragma unroll
    for (int mi = 0; mi < 2; ++mi)
#pragma unroll
      for (int r = 0; r < 4; ++r) {
        const int row = m0 + wm * 32 + mi * 16 + lg * 4 + r;
        const bool has = stats[row].x > 0;
#pragma unroll
        for (int ni = 0; ni < 2; ++ni) {
          const int col = n0 + wn * 32 + ni * 16 + lr;
          const float sv = states[(size_t)row * D_DIM + col];
          float o = has ? sv + 0.1f * (acc[mi][ni][r] + b2[org * D_DIM + col]) : sv;
          out[(size_t)row * 261 + col] = o;
        }
      }
  } else {
    const int i = (b - 288) * 4 + w;   // agent
    const int4 stv = stats[i];
    const int cnt = stv.x, mass = stv.y, fi = stv.z, enemy = stv.w;
    float po = 0.f, pin = 0.f;
    if (cnt > 0) {
      short8 av = ((const short8*)(Abf + (size_t)i * H_DIM))[l];
      short8 bv = ((const short8*)(Bbf + (size_t)i * H_DIM))[l];
      const int nn = cnt < NB_CAP ? cnt : NB_CAP;
      for (int s = 0; s < nn; ++s) {
        const int j = nb[i * NB_CAP + s];
        short8 bj = ((const short8*)(Bbf + (size_t)j * H_DIM))[l];
        short8 aj = ((const short8*)(Abf + (size_t)j * H_DIM))[l];
#pragma unroll
        for (int k2 = 0; k2 < 8; ++k2) {
          po  += bf2f((ushort_t)av[k2]) * bf2f((ushort_t)bj[k2]);
          pin += bf2f((ushort_t)bv[k2]) * bf2f((ushort_t)aj[k2]);
        }
      }
#pragma unroll
      for (int m2 = 1; m2 < 64; m2 <<= 1) {
        po  += __shfl_xor(po,  m2, 64);
        pin += __shfl_xor(pin, m2, 64);
      }
    }
    if (l == 0) {
      const float denom = fmaxf((float)cnt, 1.0f);
      const float invs = 0.044194173824159216f;   // 1/sqrt(512)
      const float ni_v = (cnt > 0) ? (po - pin) * invs / denom : 0.f;
      const int2 p = ((const int2*)positions)[i];
      const float res = resource_grid[p.y * GRID_SZ + p.x];
      const float e = energies[i];
      const int r = roles[i];
      float e_fi   = e + 0.03f * (float)mass + 0.02f * res - 0.04f * (float)enemy - 0.01f;
      float e_mass = e * 0.98f + 0.02f * ((fi > 0) ? 1.f : 0.f) + 0.01f * res - 0.02f * (float)enemy;
      float ne = (r == 1) ? e_fi : e_mass;
      ne = fminf(fmaxf(ne, 0.f), 1.f);
      const bool can_fi = (ne > 0.5f) && (mass >= 2) && (fi == 0) && (enemy == 0);
      const bool loses = (mass < 1) || (ne < 0.15f) || (enemy > fi + 1);
      const int nr = (r == 0) ? (can_fi ? 1 : 0) : ((r == 1) ? (loses ? 0 : 1) : r);
      float* orow = out + (size_t)i * 261;
      orow[256] = ni_v;
      orow[257] = ne;
      orow[258] = (nr == 0) ? 1.f : 0.f;
      orow[259] = (nr == 1) ? 1.f : 0.f;
      orow[260] = (nr == 2) ? 1.f : 0.f;
    }
  }
}

extern "C" void kernel_launch(void* const* d_in, const int* in_sizes, int n_in,
                              void* d_out, int out_size, void* d_ws, size_t ws_size,
                              hipStream_t stream) {
  const float* states        = (const float*)d_in[0];
  const float* energies      = (const float*)d_in[1];
  const float* resource_grid = (const float*)d_in[2];
  const float* W_out         = (const float*)d_in[3];
  const float* b_out         = (const float*)d_in[4];
  const float* W_in          = (const float*)d_in[5];
  const float* b_in          = (const float*)d_in[6];
  const float* W1            = (const float*)d_in[7];
  const float* b1            = (const float*)d_in[8];
  const float* W2            = (const float*)d_in[9];
  const float* b2            = (const float*)d_in[10];
  const int*   roles         = (const int*)d_in[11];
  const int*   org_ids       = (const int*)d_in[12]; (void)org_ids;
  const int*   positions     = (const int*)d_in[13];
  float*       out           = (float*)d_out;

  char* ws = (char*)d_ws;
  ushort_t* Sc    = (ushort_t*)(ws);              //  2,359,296 B
  ushort_t* Wc    = (ushort_t*)(ws +  2359296);   //  2,359,296 B
  ushort_t* W2c   = (ushort_t*)(ws +  4718592);   //    786,432 B
  ushort_t* Hc    = (ushort_t*)(ws +  5505024);   //  4,718,592 B
  ushort_t* Abf   = (ushort_t*)(ws + 10223616);   //  4,718,592 B
  ushort_t* Bbf   = (ushort_t*)(ws + 14942208);   //  4,718,592 B
  int4*     stats = (int4*)    (ws + 19660800);   //     73,728 B
  int*      nbl   = (int*)     (ws + 19734528);   //    884,736 B  -> total 20.6 MB

  prep<<<PS_BLK + PW_BLK + PW2_BLK + SCAN_BLK, 256, 0, stream>>>(
      states, W_out, W_in, W1, W2, roles, positions, Sc, Wc, W2c, stats, nbl);
  gemm_fused<<<dim3(12, 36), 256, 0, stream>>>(Sc, Wc, b_out, b_in, b1, Abf, Bbf, Hc);
  sp_final<<<1440, 256, 0, stream>>>(Hc, W2c, b2, states, Abf, Bbf,
                                     energies, resource_grid, roles, positions,
                                     stats, nbl, out);
}